// Round 3
// baseline (336.146 us; speedup 1.0000x reference)
//
#include <hip/hip_runtime.h>
#include <cmath>

// ---------------------------------------------------------------------------
// NeuralField: hashgrid encode (8 levels x 8 feats, smoothstep) + MLP
// 64 -> 256 -> 256 -> 256 -> 1 (ReLU x3, linear out), N = 262144 points.
// R3: TILE_M=64, 256 threads, 4 waves; LDS cut to 40 KB (8 KB encode buf +
// one 32 KB activation buffer reused IN-PLACE across layers, extra mid-layer
// sync) -> 4 blocks/CU (16 waves/CU). Inter-block overlap hides barrier
// drains (R1 vs R2 evidence: 2 blocks/CU @64KB beat 1 block/CU @144KB).
// ---------------------------------------------------------------------------

#define N_LEVELS 8
#define TABLE_PAD 8192
#define TILE_M 64
#define ACT_STRIDE 256       // shorts per activation row
#define ENC_STRIDE 64        // shorts per encode row

typedef __attribute__((ext_vector_type(8))) short short8;
typedef __attribute__((ext_vector_type(4))) float float4v;

struct LevelParams {
  float scale[N_LEVELS];
  int   res[N_LEVELS];
  int   size[N_LEVELS];
};

__device__ __forceinline__ unsigned short f2bf(float f) {
  unsigned int u = __float_as_uint(f);
  u += 0x7fffu + ((u >> 16) & 1u);      // round to nearest even
  return (unsigned short)(u >> 16);
}
__device__ __forceinline__ float bf2f(unsigned short h) {
  return __uint_as_float(((unsigned int)h) << 16);
}

// Pack W (K x 256 row-major f32) -> bf16 [kb][n][ki] so one wave's B-fragment
// (16 cols x 32 k) is a contiguous, fully-coalesced 1 KB chunk.
// Wp layout: [W0p: 2*256*32][W1p: 8*256*32][W2p: 8*256*32]
__global__ void pack_weights_kernel(const float* __restrict__ W0,
                                    const float* __restrict__ W1,
                                    const float* __restrict__ W2,
                                    unsigned short* __restrict__ Wp) {
  int tid = blockIdx.x * blockDim.x + threadIdx.x;
  const float* src;
  int base, e;
  if (tid < 16384)        { src = W0; base = 0;     e = tid;         }
  else if (tid < 81920)   { src = W1; base = 16384; e = tid - 16384; }
  else if (tid < 147456)  { src = W2; base = 81920; e = tid - 81920; }
  else return;
  int ki = e & 31;
  int n  = (e >> 5) & 255;
  int kb = e >> 13;
  Wp[base + e] = f2bf(src[(kb * 32 + ki) * 256 + n]);
}

__global__ __launch_bounds__(256, 4) void neural_field_kernel(
    const float* __restrict__ x,
    const float* __restrict__ table,
    const unsigned short* __restrict__ Wp,
    const float* __restrict__ W3,
    float* __restrict__ out,
    LevelParams P) {
  // XOR-swizzled layouts (16 B granular) so A-fragment ds_read_b128s are
  // <=2-way bank conflicted (free on CDNA4):
  //   enc (stride 64):  (row, col) -> row*64  + ((chunk ^ (row&7)) *8 + col&7)
  //   act (stride 256): (row, col) -> row*256 + ((chunk ^ (row&15))*8 + col&7)
  __shared__ unsigned short bufE[TILE_M * ENC_STRIDE];   // 8 KB
  __shared__ unsigned short bufA[TILE_M * ACT_STRIDE];   // 32 KB

  const int t  = threadIdx.x;
  const int g0 = blockIdx.x * TILE_M;

  // ---------------- Phase 1: hashgrid encode -> bufE (K=64) ----------------
  {
    int p  = t & 63;       // point within tile
    int lg = t >> 6;       // 0..3 -> handles levels 2lg, 2lg+1
    float2 xy = ((const float2*)x)[g0 + p];
    for (int li = 0; li < 2; ++li) {
      int l = lg * 2 + li;
      float scale = P.scale[l];
      int res = P.res[l], size = P.size[l];
      float posx = xy.x * scale + 0.5f;
      float posy = xy.y * scale + 0.5f;
      float pgx = floorf(posx), pgy = floorf(posy);
      float fx = posx - pgx, fy = posy - pgy;
      float wx = fx * fx * (3.0f - 2.0f * fx);
      float wy = fy * fy * (3.0f - 2.0f * fy);
      int px = (int)pgx, py = (int)pgy;
      float acc[8] = {0, 0, 0, 0, 0, 0, 0, 0};
      for (int dy = 0; dy < 2; ++dy) {
        float wyv = dy ? wy : 1.0f - wy;
        for (int dx = 0; dx < 2; ++dx) {
          float wgt = (dx ? wx : 1.0f - wx) * wyv;
          int idx = (px + dx) + (py + dy) * res;
          if (idx >= size) idx -= size;   // idx < 2*size always
          const float4* tp =
              (const float4*)(table + ((size_t)l * TABLE_PAD + idx) * 8);
          float4 t0 = tp[0], t1 = tp[1];
          acc[0] += wgt * t0.x; acc[1] += wgt * t0.y;
          acc[2] += wgt * t0.z; acc[3] += wgt * t0.w;
          acc[4] += wgt * t1.x; acc[5] += wgt * t1.y;
          acc[6] += wgt * t1.z; acc[7] += wgt * t1.w;
        }
      }
      union { unsigned short s[8]; short8 v; } u;
      for (int j = 0; j < 8; ++j) u.s[j] = f2bf(acc[j]);
      int pos = (l ^ (p & 7)) * 8;        // chunk l, swizzled (8 chunks)
      *(short8*)&bufE[p * ENC_STRIDE + pos] = u.v;
    }
  }

  const int lane  = t & 63;
  const int w     = t >> 6;       // 0..3
  const int l15   = lane & 15;
  const int quad  = lane >> 4;
  const int wbase = w * 64;       // this wave's 64 output columns

  // ------------- MFMA layer: [64 x K] @ [K x 256] + ReLU -------------------
  // Each wave computes a 64x64 sub-tile (4x4 grid of 16x16x32 MFMAs).
  // If inplace, a mid-layer barrier separates the K-loop reads from the
  // epilogue writes into the same buffer.
  auto run_layer = [&](const unsigned short* inb, int in_stride, int smask,
                       unsigned short* outb, const unsigned short* Wpl,
                       int KB, bool inplace) {
    float4v acc[4][4];
    for (int mt = 0; mt < 4; ++mt)
      for (int nt = 0; nt < 4; ++nt)
        acc[mt][nt] = (float4v){0.f, 0.f, 0.f, 0.f};

    // Preload B for kb=0
    short8 bc[4];
    for (int nt = 0; nt < 4; ++nt) {
      int n = wbase + nt * 16 + l15;
      bc[nt] = *(const short8*)&Wpl[(0 * 256 + n) * 32 + quad * 8];
    }

    for (int kb = 0; kb < KB; ++kb) {
      // Prefetch next kb's B fragments (L2 hits) before the MFMA bundle.
      short8 bn[4];
      int kb2 = (kb + 1 < KB) ? kb + 1 : kb;
      for (int nt = 0; nt < 4; ++nt) {
        int n = wbase + nt * 16 + l15;
        bn[nt] = *(const short8*)&Wpl[(kb2 * 256 + n) * 32 + quad * 8];
      }
      short8 a[4];
      int kchunk = kb * 4 + quad;
      for (int mt = 0; mt < 4; ++mt) {
        int row = mt * 16 + l15;
        int pos = (kchunk ^ (row & smask)) * 8;
        a[mt] = *(const short8*)&inb[row * in_stride + pos];
      }
      for (int mt = 0; mt < 4; ++mt)
        for (int nt = 0; nt < 4; ++nt)
          acc[mt][nt] = __builtin_amdgcn_mfma_f32_16x16x32_bf16(
              a[mt], bc[nt], acc[mt][nt], 0, 0, 0);
      for (int nt = 0; nt < 4; ++nt) bc[nt] = bn[nt];
    }

    if (inplace) __syncthreads();   // all reads done before overwrite

    // Epilogue: ReLU, cvt bf16, store C (col = lane&15, row = quad*4+reg)
    for (int mt = 0; mt < 4; ++mt) {
      for (int nt = 0; nt < 4; ++nt) {
        int col = wbase + nt * 16 + l15;
        int chunk = col >> 3, within = col & 7;
        for (int r = 0; r < 4; ++r) {
          int row = mt * 16 + quad * 4 + r;
          float v = acc[mt][nt][r];
          v = v > 0.f ? v : 0.f;
          int pos = (chunk ^ (row & 15)) * 8 + within;
          outb[row * ACT_STRIDE + pos] = f2bf(v);
        }
      }
    }
  };

  __syncthreads();
  run_layer(bufE, ENC_STRIDE, 7,  bufA, Wp,         2, false);  // layer 0
  __syncthreads();
  run_layer(bufA, ACT_STRIDE, 15, bufA, Wp + 16384, 8, true);   // layer 1
  __syncthreads();
  run_layer(bufA, ACT_STRIDE, 15, bufA, Wp + 81920, 8, true);   // layer 2
  __syncthreads();

  // ---------------- Final layer: out[p] = h2[p] . W3 -----------------------
  {
    int p = t >> 2;          // point within tile (0..63)
    int q = t & 3;           // quarter of K=256
    float s = 0.f;
    for (int c8 = 0; c8 < 8; ++c8) {
      int chunk = q * 8 + c8;
      int pos = (chunk ^ (p & 15)) * 8;
      short8 h = *(const short8*)&bufA[p * ACT_STRIDE + pos];
      float4 w0v = *(const float4*)(W3 + chunk * 8);
      float4 w1v = *(const float4*)(W3 + chunk * 8 + 4);
      s += bf2f((unsigned short)h[0]) * w0v.x;
      s += bf2f((unsigned short)h[1]) * w0v.y;
      s += bf2f((unsigned short)h[2]) * w0v.z;
      s += bf2f((unsigned short)h[3]) * w0v.w;
      s += bf2f((unsigned short)h[4]) * w1v.x;
      s += bf2f((unsigned short)h[5]) * w1v.y;
      s += bf2f((unsigned short)h[6]) * w1v.z;
      s += bf2f((unsigned short)h[7]) * w1v.w;
    }
    s += __shfl_xor(s, 1);
    s += __shfl_xor(s, 2);
    if (q == 0) out[g0 + p] = s;
  }
}

extern "C" void kernel_launch(void* const* d_in, const int* in_sizes, int n_in,
                              void* d_out, int out_size, void* d_ws,
                              size_t ws_size, hipStream_t stream) {
  const float* x     = (const float*)d_in[0];
  const float* table = (const float*)d_in[1];
  const float* W0    = (const float*)d_in[2];
  const float* W1    = (const float*)d_in[3];
  const float* W2    = (const float*)d_in[4];
  const float* W3    = (const float*)d_in[5];
  float* out = (float*)d_out;
  int N = in_sizes[0] / 2;

  unsigned short* Wp = (unsigned short*)d_ws;   // 147456 bf16 = 288 KB

  // Level params, double precision to match the Python reference exactly.
  LevelParams P;
  const double c = 1.2599210739135742;
  double m = 1.0;
  for (int l = 0; l < N_LEVELS; ++l) {
    double scale_d = 16.0 * m - 1.0;
    int res = (int)std::ceil(scale_d) + 1;
    long long sz = ((long long)res * res + 7) / 8 * 8;
    if (sz > (1LL << 19)) sz = 1LL << 19;
    P.scale[l] = (float)scale_d;
    P.res[l]   = res;
    P.size[l]  = (int)sz;
    m *= c;
  }

  hipLaunchKernelGGL(pack_weights_kernel, dim3(576), dim3(256), 0, stream,
                     W0, W1, W2, Wp);
  hipLaunchKernelGGL(neural_field_kernel, dim3(N / TILE_M), dim3(256), 0,
                     stream, x, table, Wp, W3, out, P);
}

// Round 4
// 270.589 us; speedup vs baseline: 1.2423x; 1.2423x over previous
//
#include <hip/hip_runtime.h>
#include <cmath>

// ---------------------------------------------------------------------------
// NeuralField: hashgrid encode (8 levels x 8 feats, smoothstep) + MLP
// 64 -> 256 -> 256 -> 256 -> 1 (ReLU x3, linear out), N = 262144 points.
// R4: R3's 40 KB LDS scheme (8 KB enc + 32 KB in-place act buffer) but
// __launch_bounds__(256,3): R3's (256,4) capped regs at 128/wave and the
// compiler SPILLED accumulators to scratch (FETCH 310 MB, WRITE 455 MB,
// VGPR_Count=64). (256,3) gives ~170 regs/wave -> no spill, 3 blocks/CU.
// Manual B-prefetch removed (register pressure; compiler schedules loads).
// ---------------------------------------------------------------------------

#define N_LEVELS 8
#define TABLE_PAD 8192
#define TILE_M 64
#define ACT_STRIDE 256       // shorts per activation row
#define ENC_STRIDE 64        // shorts per encode row

typedef __attribute__((ext_vector_type(8))) short short8;
typedef __attribute__((ext_vector_type(4))) float float4v;

struct LevelParams {
  float scale[N_LEVELS];
  int   res[N_LEVELS];
  int   size[N_LEVELS];
};

__device__ __forceinline__ unsigned short f2bf(float f) {
  unsigned int u = __float_as_uint(f);
  u += 0x7fffu + ((u >> 16) & 1u);      // round to nearest even
  return (unsigned short)(u >> 16);
}
__device__ __forceinline__ float bf2f(unsigned short h) {
  return __uint_as_float(((unsigned int)h) << 16);
}

// Pack W (K x 256 row-major f32) -> bf16 [kb][n][ki] so one wave's B-fragment
// (16 cols x 32 k) is a contiguous, fully-coalesced 1 KB chunk.
// Wp layout: [W0p: 2*256*32][W1p: 8*256*32][W2p: 8*256*32]
__global__ void pack_weights_kernel(const float* __restrict__ W0,
                                    const float* __restrict__ W1,
                                    const float* __restrict__ W2,
                                    unsigned short* __restrict__ Wp) {
  int tid = blockIdx.x * blockDim.x + threadIdx.x;
  const float* src;
  int base, e;
  if (tid < 16384)        { src = W0; base = 0;     e = tid;         }
  else if (tid < 81920)   { src = W1; base = 16384; e = tid - 16384; }
  else if (tid < 147456)  { src = W2; base = 81920; e = tid - 81920; }
  else return;
  int ki = e & 31;
  int n  = (e >> 5) & 255;
  int kb = e >> 13;
  Wp[base + e] = f2bf(src[(kb * 32 + ki) * 256 + n]);
}

__global__ __launch_bounds__(256, 3) void neural_field_kernel(
    const float* __restrict__ x,
    const float* __restrict__ table,
    const unsigned short* __restrict__ Wp,
    const float* __restrict__ W3,
    float* __restrict__ out,
    LevelParams P) {
  // XOR-swizzled layouts (16 B granular) so A-fragment ds_read_b128s are
  // <=2-way bank conflicted (free on CDNA4):
  //   enc (stride 64):  (row, col) -> row*64  + ((chunk ^ (row&7)) *8 + col&7)
  //   act (stride 256): (row, col) -> row*256 + ((chunk ^ (row&15))*8 + col&7)
  __shared__ unsigned short bufE[TILE_M * ENC_STRIDE];   // 8 KB
  __shared__ unsigned short bufA[TILE_M * ACT_STRIDE];   // 32 KB

  const int t  = threadIdx.x;
  const int g0 = blockIdx.x * TILE_M;

  // ---------------- Phase 1: hashgrid encode -> bufE (K=64) ----------------
  {
    int p  = t & 63;       // point within tile
    int lg = t >> 6;       // 0..3 -> handles levels 2lg, 2lg+1
    float2 xy = ((const float2*)x)[g0 + p];
    for (int li = 0; li < 2; ++li) {
      int l = lg * 2 + li;
      float scale = P.scale[l];
      int res = P.res[l], size = P.size[l];
      float posx = xy.x * scale + 0.5f;
      float posy = xy.y * scale + 0.5f;
      float pgx = floorf(posx), pgy = floorf(posy);
      float fx = posx - pgx, fy = posy - pgy;
      float wx = fx * fx * (3.0f - 2.0f * fx);
      float wy = fy * fy * (3.0f - 2.0f * fy);
      int px = (int)pgx, py = (int)pgy;
      float acc[8] = {0, 0, 0, 0, 0, 0, 0, 0};
      for (int dy = 0; dy < 2; ++dy) {
        float wyv = dy ? wy : 1.0f - wy;
        for (int dx = 0; dx < 2; ++dx) {
          float wgt = (dx ? wx : 1.0f - wx) * wyv;
          int idx = (px + dx) + (py + dy) * res;
          if (idx >= size) idx -= size;   // idx < 2*size always
          const float4* tp =
              (const float4*)(table + ((size_t)l * TABLE_PAD + idx) * 8);
          float4 t0 = tp[0], t1 = tp[1];
          acc[0] += wgt * t0.x; acc[1] += wgt * t0.y;
          acc[2] += wgt * t0.z; acc[3] += wgt * t0.w;
          acc[4] += wgt * t1.x; acc[5] += wgt * t1.y;
          acc[6] += wgt * t1.z; acc[7] += wgt * t1.w;
        }
      }
      union { unsigned short s[8]; short8 v; } u;
      for (int j = 0; j < 8; ++j) u.s[j] = f2bf(acc[j]);
      int pos = (l ^ (p & 7)) * 8;        // chunk l, swizzled (8 chunks)
      *(short8*)&bufE[p * ENC_STRIDE + pos] = u.v;
    }
  }

  const int lane  = t & 63;
  const int w     = t >> 6;       // 0..3
  const int l15   = lane & 15;
  const int quad  = lane >> 4;
  const int wbase = w * 64;       // this wave's 64 output columns

  // ------------- MFMA layer: [64 x K] @ [K x 256] + ReLU -------------------
  // Each wave computes a 64x64 sub-tile (4x4 grid of 16x16x32 MFMAs).
  // If inplace, a mid-layer barrier separates the K-loop reads from the
  // epilogue writes into the same buffer.
  auto run_layer = [&](const unsigned short* inb, int in_stride, int smask,
                       unsigned short* outb, const unsigned short* Wpl,
                       int KB, bool inplace) {
    float4v acc[4][4];
    for (int mt = 0; mt < 4; ++mt)
      for (int nt = 0; nt < 4; ++nt)
        acc[mt][nt] = (float4v){0.f, 0.f, 0.f, 0.f};

    for (int kb = 0; kb < KB; ++kb) {
      short8 a[4], b[4];
      for (int nt = 0; nt < 4; ++nt) {
        int n = wbase + nt * 16 + l15;
        b[nt] = *(const short8*)&Wpl[(kb * 256 + n) * 32 + quad * 8];
      }
      int kchunk = kb * 4 + quad;
      for (int mt = 0; mt < 4; ++mt) {
        int row = mt * 16 + l15;
        int pos = (kchunk ^ (row & smask)) * 8;
        a[mt] = *(const short8*)&inb[row * in_stride + pos];
      }
      for (int mt = 0; mt < 4; ++mt)
        for (int nt = 0; nt < 4; ++nt)
          acc[mt][nt] = __builtin_amdgcn_mfma_f32_16x16x32_bf16(
              a[mt], b[nt], acc[mt][nt], 0, 0, 0);
    }

    if (inplace) __syncthreads();   // all reads done before overwrite

    // Epilogue: ReLU, cvt bf16, store C (col = lane&15, row = quad*4+reg)
    for (int mt = 0; mt < 4; ++mt) {
      for (int nt = 0; nt < 4; ++nt) {
        int col = wbase + nt * 16 + l15;
        int chunk = col >> 3, within = col & 7;
        for (int r = 0; r < 4; ++r) {
          int row = mt * 16 + quad * 4 + r;
          float v = acc[mt][nt][r];
          v = v > 0.f ? v : 0.f;
          int pos = (chunk ^ (row & 15)) * 8 + within;
          outb[row * ACT_STRIDE + pos] = f2bf(v);
        }
      }
    }
  };

  __syncthreads();
  run_layer(bufE, ENC_STRIDE, 7,  bufA, Wp,         2, false);  // layer 0
  __syncthreads();
  run_layer(bufA, ACT_STRIDE, 15, bufA, Wp + 16384, 8, true);   // layer 1
  __syncthreads();
  run_layer(bufA, ACT_STRIDE, 15, bufA, Wp + 81920, 8, true);   // layer 2
  __syncthreads();

  // ---------------- Final layer: out[p] = h2[p] . W3 -----------------------
  {
    int p = t >> 2;          // point within tile (0..63)
    int q = t & 3;           // quarter of K=256
    float s = 0.f;
    for (int c8 = 0; c8 < 8; ++c8) {
      int chunk = q * 8 + c8;
      int pos = (chunk ^ (p & 15)) * 8;
      short8 h = *(const short8*)&bufA[p * ACT_STRIDE + pos];
      float4 w0v = *(const float4*)(W3 + chunk * 8);
      float4 w1v = *(const float4*)(W3 + chunk * 8 + 4);
      s += bf2f((unsigned short)h[0]) * w0v.x;
      s += bf2f((unsigned short)h[1]) * w0v.y;
      s += bf2f((unsigned short)h[2]) * w0v.z;
      s += bf2f((unsigned short)h[3]) * w0v.w;
      s += bf2f((unsigned short)h[4]) * w1v.x;
      s += bf2f((unsigned short)h[5]) * w1v.y;
      s += bf2f((unsigned short)h[6]) * w1v.z;
      s += bf2f((unsigned short)h[7]) * w1v.w;
    }
    s += __shfl_xor(s, 1);
    s += __shfl_xor(s, 2);
    if (q == 0) out[g0 + p] = s;
  }
}

extern "C" void kernel_launch(void* const* d_in, const int* in_sizes, int n_in,
                              void* d_out, int out_size, void* d_ws,
                              size_t ws_size, hipStream_t stream) {
  const float* x     = (const float*)d_in[0];
  const float* table = (const float*)d_in[1];
  const float* W0    = (const float*)d_in[2];
  const float* W1    = (const float*)d_in[3];
  const float* W2    = (const float*)d_in[4];
  const float* W3    = (const float*)d_in[5];
  float* out = (float*)d_out;
  int N = in_sizes[0] / 2;

  unsigned short* Wp = (unsigned short*)d_ws;   // 147456 bf16 = 288 KB

  // Level params, double precision to match the Python reference exactly.
  LevelParams P;
  const double c = 1.2599210739135742;
  double m = 1.0;
  for (int l = 0; l < N_LEVELS; ++l) {
    double scale_d = 16.0 * m - 1.0;
    int res = (int)std::ceil(scale_d) + 1;
    long long sz = ((long long)res * res + 7) / 8 * 8;
    if (sz > (1LL << 19)) sz = 1LL << 19;
    P.scale[l] = (float)scale_d;
    P.res[l]   = res;
    P.size[l]  = (int)sz;
    m *= c;
  }

  hipLaunchKernelGGL(pack_weights_kernel, dim3(576), dim3(256), 0, stream,
                     W0, W1, W2, Wp);
  hipLaunchKernelGGL(neural_field_kernel, dim3(N / TILE_M), dim3(256), 0,
                     stream, x, table, Wp, W3, out, P);
}

// Round 5
// 203.563 us; speedup vs baseline: 1.6513x; 1.3293x over previous
//
#include <hip/hip_runtime.h>
#include <cmath>

// ---------------------------------------------------------------------------
// NeuralField: hashgrid encode (8 levels x 8 feats, smoothstep) + MLP
// 64 -> 256 -> 256 -> 256 -> 1 (ReLU x3, linear out), N = 262144 points.
// R5: transposed MFMA formulation. Each layer computes H^T = W^T @ X^T
// (A = weight fragments [n][k], B = activation fragments [m][k]); the MFMA
// C-layout's 4-row runs then lie along the FEATURE dim (= next layer's k),
// so the epilogue is 16 ds_write_b64 per wave/layer instead of 64 scalar
// ds_write_b16 with 8-way conflicts (R1's hidden cost: epilogue ~2x MFMA
// time). Layouts/packing otherwise identical to R1. (256,2), 72 KB LDS,
// 2 blocks/CU — the only no-spill configuration proven so far (R3/R4:
// tighter caps spill accumulators -> 300-700 MB scratch HBM traffic).
// ---------------------------------------------------------------------------

#define N_LEVELS 8
#define TABLE_PAD 8192
#define TILE_M 64
#define ACT_STRIDE 256       // shorts per activation row
#define ENC_STRIDE 64        // shorts per encode row

typedef __attribute__((ext_vector_type(8))) short short8;
typedef __attribute__((ext_vector_type(4))) short short4v;
typedef __attribute__((ext_vector_type(4))) float float4v;

struct LevelParams {
  float scale[N_LEVELS];
  int   res[N_LEVELS];
  int   size[N_LEVELS];
};

__device__ __forceinline__ unsigned short f2bf(float f) {
  unsigned int u = __float_as_uint(f);
  u += 0x7fffu + ((u >> 16) & 1u);      // round to nearest even
  return (unsigned short)(u >> 16);
}
__device__ __forceinline__ float bf2f(unsigned short h) {
  return __uint_as_float(((unsigned int)h) << 16);
}

// Pack W (K x 256 row-major f32) -> bf16 [kb][n][ki]: one lane's 16 B A-frag
// (output-feature n, k-chunk) is contiguous; a wave's 16 n x 32 k tile is a
// coalesced 1 KB chunk. Wp layout: [W0p: 2*256*32][W1p+W2p: 8*256*32 each]
__global__ void pack_weights_kernel(const float* __restrict__ W0,
                                    const float* __restrict__ W1,
                                    const float* __restrict__ W2,
                                    unsigned short* __restrict__ Wp) {
  int tid = blockIdx.x * blockDim.x + threadIdx.x;
  const float* src;
  int base, e;
  if (tid < 16384)        { src = W0; base = 0;     e = tid;         }
  else if (tid < 81920)   { src = W1; base = 16384; e = tid - 16384; }
  else if (tid < 147456)  { src = W2; base = 81920; e = tid - 81920; }
  else return;
  int ki = e & 31;
  int n  = (e >> 5) & 255;
  int kb = e >> 13;
  Wp[base + e] = f2bf(src[(kb * 32 + ki) * 256 + n]);
}

__global__ __launch_bounds__(256, 2) void neural_field_kernel(
    const float* __restrict__ x,
    const float* __restrict__ table,
    const unsigned short* __restrict__ Wp,
    const float* __restrict__ W3,
    float* __restrict__ out,
    LevelParams P) {
  // XOR-swizzled layouts (16 B granular), data stored [point m][feature k]:
  //   enc (stride 64):  (m, k) -> m*64  + ((chunk ^ (m&7)) *8 + k&7)
  //   act (stride 256): (m, k) -> m*256 + ((chunk ^ (m&15))*8 + k&7)
  // B-fragment ds_read_b128s land <=2-way bank conflicted (free on CDNA4).
  __shared__ unsigned short bufE[TILE_M * ENC_STRIDE];   // 8 KB
  __shared__ unsigned short bufA[TILE_M * ACT_STRIDE];   // 32 KB
  __shared__ unsigned short bufB[TILE_M * ACT_STRIDE];   // 32 KB

  const int t  = threadIdx.x;
  const int g0 = blockIdx.x * TILE_M;

  // ---------------- Phase 1: hashgrid encode -> bufE (K=64) ----------------
  {
    int p  = t & 63;       // point within tile
    int lg = t >> 6;       // 0..3 -> handles levels 2lg, 2lg+1
    float2 xy = ((const float2*)x)[g0 + p];
    for (int li = 0; li < 2; ++li) {
      int l = lg * 2 + li;
      float scale = P.scale[l];
      int res = P.res[l], size = P.size[l];
      float posx = xy.x * scale + 0.5f;
      float posy = xy.y * scale + 0.5f;
      float pgx = floorf(posx), pgy = floorf(posy);
      float fx = posx - pgx, fy = posy - pgy;
      float wx = fx * fx * (3.0f - 2.0f * fx);
      float wy = fy * fy * (3.0f - 2.0f * fy);
      int px = (int)pgx, py = (int)pgy;
      float acc[8] = {0, 0, 0, 0, 0, 0, 0, 0};
      for (int dy = 0; dy < 2; ++dy) {
        float wyv = dy ? wy : 1.0f - wy;
        for (int dx = 0; dx < 2; ++dx) {
          float wgt = (dx ? wx : 1.0f - wx) * wyv;
          int idx = (px + dx) + (py + dy) * res;
          if (idx >= size) idx -= size;   // idx < 2*size always
          const float4* tp =
              (const float4*)(table + ((size_t)l * TABLE_PAD + idx) * 8);
          float4 t0 = tp[0], t1 = tp[1];
          acc[0] += wgt * t0.x; acc[1] += wgt * t0.y;
          acc[2] += wgt * t0.z; acc[3] += wgt * t0.w;
          acc[4] += wgt * t1.x; acc[5] += wgt * t1.y;
          acc[6] += wgt * t1.z; acc[7] += wgt * t1.w;
        }
      }
      union { unsigned short s[8]; short8 v; } u;
      for (int j = 0; j < 8; ++j) u.s[j] = f2bf(acc[j]);
      int pos = (l ^ (p & 7)) * 8;        // chunk l, swizzled (8 chunks)
      *(short8*)&bufE[p * ENC_STRIDE + pos] = u.v;
    }
  }

  const int lane  = t & 63;
  const int w     = t >> 6;       // 0..3
  const int l15   = lane & 15;
  const int quad  = lane >> 4;
  const int wbase = w * 64;       // this wave's 64 OUTPUT FEATURES

  // ------- MFMA layer (transposed): D = W^T[64 x K] @ X^T[K x 64] ----------
  // A-frag = weights: lane row n = wbase+ft*16+l15, k = quad*8..+7.
  // B-frag = acts:    lane col m = pt*16+l15,       k = quad*8..+7.
  // D runs along n (feature dim) -> epilogue packs 4 bf16 -> one b64 write
  // per tile, already in the [m][k-contiguous] layout the next layer reads.
  auto run_layer = [&](const unsigned short* inb, int in_stride, int smask,
                       unsigned short* outb, const unsigned short* Wpl,
                       int KB) {
    float4v acc[4][4];   // [ft][pt]
    for (int ft = 0; ft < 4; ++ft)
      for (int pt = 0; pt < 4; ++pt)
        acc[ft][pt] = (float4v){0.f, 0.f, 0.f, 0.f};

    for (int kb = 0; kb < KB; ++kb) {
      short8 wf[4], af[4];
      for (int ft = 0; ft < 4; ++ft) {
        int n = wbase + ft * 16 + l15;
        wf[ft] = *(const short8*)&Wpl[(kb * 256 + n) * 32 + quad * 8];
      }
      int kchunk = kb * 4 + quad;
      for (int pt = 0; pt < 4; ++pt) {
        int m = pt * 16 + l15;
        int pos = (kchunk ^ (m & smask)) * 8;
        af[pt] = *(const short8*)&inb[m * in_stride + pos];
      }
      for (int ft = 0; ft < 4; ++ft)
        for (int pt = 0; pt < 4; ++pt)
          acc[ft][pt] = __builtin_amdgcn_mfma_f32_16x16x32_bf16(
              wf[ft], af[pt], acc[ft][pt], 0, 0, 0);
    }

    // Epilogue: ReLU + bf16, one ds_write_b64 per tile.
    // D tile (ft,pt): lane holds rows n0..n0+3 (n0 = wbase+ft*16+quad*4) of
    // col m = pt*16+l15 -> 4 consecutive k-dim shorts in act layout.
    for (int ft = 0; ft < 4; ++ft) {
      int n0 = wbase + ft * 16 + quad * 4;
      int chunk = n0 >> 3, within = n0 & 7;       // within in {0,4}
      for (int pt = 0; pt < 4; ++pt) {
        int m = pt * 16 + l15;
        union { unsigned short s[4]; short4v v; } u;
        for (int r = 0; r < 4; ++r) {
          float v = acc[ft][pt][r];
          u.s[r] = f2bf(v > 0.f ? v : 0.f);
        }
        int pos = (chunk ^ (m & 15)) * 8 + within;
        *(short4v*)&outb[m * ACT_STRIDE + pos] = u.v;
      }
    }
  };

  __syncthreads();
  run_layer(bufE, ENC_STRIDE, 7,  bufA, Wp,         2);  // layer 0
  __syncthreads();
  run_layer(bufA, ACT_STRIDE, 15, bufB, Wp + 16384, 8);  // layer 1
  __syncthreads();
  run_layer(bufB, ACT_STRIDE, 15, bufA, Wp + 81920, 8);  // layer 2
  __syncthreads();

  // ---------------- Final layer: out[p] = h2[p] . W3 -----------------------
  {
    int p = t >> 2;          // point within tile (0..63)
    int q = t & 3;           // quarter of K=256
    float s = 0.f;
    for (int c8 = 0; c8 < 8; ++c8) {
      int chunk = q * 8 + c8;
      int pos = (chunk ^ (p & 15)) * 8;
      short8 h = *(const short8*)&bufA[p * ACT_STRIDE + pos];
      float4 w0v = *(const float4*)(W3 + chunk * 8);
      float4 w1v = *(const float4*)(W3 + chunk * 8 + 4);
      s += bf2f((unsigned short)h[0]) * w0v.x;
      s += bf2f((unsigned short)h[1]) * w0v.y;
      s += bf2f((unsigned short)h[2]) * w0v.z;
      s += bf2f((unsigned short)h[3]) * w0v.w;
      s += bf2f((unsigned short)h[4]) * w1v.x;
      s += bf2f((unsigned short)h[5]) * w1v.y;
      s += bf2f((unsigned short)h[6]) * w1v.z;
      s += bf2f((unsigned short)h[7]) * w1v.w;
    }
    s += __shfl_xor(s, 1);
    s += __shfl_xor(s, 2);
    if (q == 0) out[g0 + p] = s;
  }
}

extern "C" void kernel_launch(void* const* d_in, const int* in_sizes, int n_in,
                              void* d_out, int out_size, void* d_ws,
                              size_t ws_size, hipStream_t stream) {
  const float* x     = (const float*)d_in[0];
  const float* table = (const float*)d_in[1];
  const float* W0    = (const float*)d_in[2];
  const float* W1    = (const float*)d_in[3];
  const float* W2    = (const float*)d_in[4];
  const float* W3    = (const float*)d_in[5];
  float* out = (float*)d_out;
  int N = in_sizes[0] / 2;

  unsigned short* Wp = (unsigned short*)d_ws;   // 147456 bf16 = 288 KB

  // Level params, double precision to match the Python reference exactly.
  LevelParams P;
  const double c = 1.2599210739135742;
  double m = 1.0;
  for (int l = 0; l < N_LEVELS; ++l) {
    double scale_d = 16.0 * m - 1.0;
    int res = (int)std::ceil(scale_d) + 1;
    long long sz = ((long long)res * res + 7) / 8 * 8;
    if (sz > (1LL << 19)) sz = 1LL << 19;
    P.scale[l] = (float)scale_d;
    P.res[l]   = res;
    P.size[l]  = (int)sz;
    m *= c;
  }

  hipLaunchKernelGGL(pack_weights_kernel, dim3(576), dim3(256), 0, stream,
                     W0, W1, W2, Wp);
  hipLaunchKernelGGL(neural_field_kernel, dim3(N / TILE_M), dim3(256), 0,
                     stream, x, table, Wp, W3, out, P);
}